// Round 8
// baseline (483.196 us; speedup 1.0000x reference)
//
#include <hip/hip_runtime.h>
#include <math.h>

#define NS   64
#define NOBS 10000
#define NB   256
#define TMAX 2048

// workspace layout (floats)
#define PIP_OFF 0
#define ASW_OFF 64                    // pk-paired swizzled A_prob, 4096 floats
#define LSE_OFF (64 + 4096)
#define ET_OFF  (64 + 4096 + 64)

__device__ __forceinline__ float wsum64(float v) {
  v += __shfl_xor(v, 1);
  v += __shfl_xor(v, 2);
  v += __shfl_xor(v, 4);
  v += __shfl_xor(v, 8);
  v += __shfl_xor(v, 16);
  v += __shfl_xor(v, 32);
  return v;
}

// DPP row_ror:N within 16-lane rows. Direction probed at prep time.
#define DPPROR(S, N)                                                           \
  __int_as_float(__builtin_amdgcn_update_dpp(                                  \
      0, __float_as_int(S), 0x120 + (N), 0xF, 0xF, true))

// packed fp32 ops; src1's LO word broadcast to both halves via op_sel.
// Non-tied asm form (D may legally differ from S2 in VOP3P).
#define PKMUL(ACC, AP, RT)                                                     \
  asm("v_pk_mul_f32 %0, %1, %2 op_sel:[0,0] op_sel_hi:[1,0]"                   \
      : "=v"(ACC) : "v"(AP), "v"(RT))
#define PKFMA(ACC, AP, RT)                                                     \
  asm("v_pk_fma_f32 %0, %1, %2, %3 op_sel:[0,0,0] op_sel_hi:[1,0,1]"           \
      : "=v"(ACC) : "v"(AP), "v"(RT), "v"(ACC))
#define PKADD(D, X, Y)                                                         \
  asm("v_pk_add_f32 %0, %1, %2" : "=v"(D) : "v"(X), "v"(Y))

// full xor-32 + xor-16 lane sum via gfx950 permlane swaps (parity-agnostic).
#define COMB(Q) ({                                                             \
    float a32_ = (Q); float b32_;                                              \
    asm("v_mov_b32 %0, %1" : "=v"(b32_) : "v"(a32_));                          \
    asm("v_permlane32_swap_b32 %0, %1" : "+v"(a32_), "+v"(b32_));              \
    float s32_ = a32_ + b32_;                                                  \
    float a16_ = s32_; float b16_;                                             \
    asm("v_mov_b32 %0, %1" : "=v"(b16_) : "v"(s32_));                          \
    asm("v_permlane16_swap_b32 %0, %1" : "+v"(a16_), "+v"(b16_));              \
    a16_ + b16_; })

// ---------------- precompute: softmax(pi), column-softmax(A), pk swizzle ---
__global__ __launch_bounds__(64) void prep_small(const float* __restrict__ pi,
                                                 const float* __restrict__ A,
                                                 float* __restrict__ ws) {
  const int l = threadIdx.x;  // 0..63
  const int r = l & 15, c = l >> 4;
  float p = pi[l];
  float m = p;
  m = fmaxf(m, __shfl_xor(m, 1));
  m = fmaxf(m, __shfl_xor(m, 2));
  m = fmaxf(m, __shfl_xor(m, 4));
  m = fmaxf(m, __shfl_xor(m, 8));
  m = fmaxf(m, __shfl_xor(m, 16));
  m = fmaxf(m, __shfl_xor(m, 32));
  float ex = expf(p - m);
  float s = wsum64(ex);
  ws[PIP_OFF + l] = ex / s;

  __shared__ float Ap[NS * NS];
  float cm = -3.0e38f;
  for (int i = 0; i < NS; ++i) cm = fmaxf(cm, A[i * NS + l]);
  float cs = 0.f;
  for (int i = 0; i < NS; ++i) cs += expf(A[i * NS + l] - cm);
  float inv = 1.0f / cs;
  for (int i = 0; i < NS; ++i) Ap[i * NS + l] = expf(A[i * NS + l] - cm) * inv;
  __syncthreads();

  // probe the hardware's row_ror direction: does lane l receive (l-1)&15 ?
  const int probe = __builtin_amdgcn_update_dpp(0, l, 0x121, 0xF, 0xF, true);
  const int dir = ((probe & 15) == ((r - 1) & 15)) ? 1 : -1;  // uniform

  // systolic swizzle + pk pairing:
  //  [2j,2j+1]       = (Ag0[j], Ag1[j])   j=0..15
  //  [32+2j,32+2j+1] = (Ag2[j], Ag3[j])
  // where Agk[j] = Ap[(r+16k)*NS + 16c + ((r - dir*j)&15)]
  for (int j = 0; j < 16; ++j) {
    const int col = 16 * c + ((r - dir * j) & 15);
    ws[ASW_OFF + l * 64 + 2 * j]          = Ap[(r + 0)  * NS + col];
    ws[ASW_OFF + l * 64 + 2 * j + 1]      = Ap[(r + 16) * NS + col];
    ws[ASW_OFF + l * 64 + 32 + 2 * j]     = Ap[(r + 32) * NS + col];
    ws[ASW_OFF + l * 64 + 32 + 2 * j + 1] = Ap[(r + 48) * NS + col];
  }
}

// ---------------- precompute: per-state emission logsumexp ----------------
__global__ __launch_bounds__(256) void emis_lse(const float* __restrict__ E,
                                                float* __restrict__ ws) {
  const int s = blockIdx.x;  // state
  const float* row = E + (size_t)s * NOBS;
  __shared__ float red[4];
  float m = -3.0e38f;
  for (int o = threadIdx.x; o < NOBS; o += 256) m = fmaxf(m, row[o]);
  m = fmaxf(m, __shfl_xor(m, 1));
  m = fmaxf(m, __shfl_xor(m, 2));
  m = fmaxf(m, __shfl_xor(m, 4));
  m = fmaxf(m, __shfl_xor(m, 8));
  m = fmaxf(m, __shfl_xor(m, 16));
  m = fmaxf(m, __shfl_xor(m, 32));
  const int wid = threadIdx.x >> 6;
  if ((threadIdx.x & 63) == 0) red[wid] = m;
  __syncthreads();
  m = fmaxf(fmaxf(red[0], red[1]), fmaxf(red[2], red[3]));
  __syncthreads();
  float sum = 0.f;
  for (int o = threadIdx.x; o < NOBS; o += 256) sum += expf(row[o] - m);
  sum = wsum64(sum);
  if ((threadIdx.x & 63) == 0) red[wid] = sum;
  __syncthreads();
  if (threadIdx.x == 0)
    ws[LSE_OFF + s] = m + logf(red[0] + red[1] + red[2] + red[3]);
}

// ---------------- precompute: EprobT[obs*64 + s] = exp(E[s,obs] - lse[s]) ----
__global__ __launch_bounds__(256) void emis_fill(const float* __restrict__ E,
                                                 float* __restrict__ ws) {
  const int idx = blockIdx.x * 256 + threadIdx.x;  // = obs*64 + s
  if (idx >= NS * NOBS) return;
  const int s = idx & 63;
  const int obs = idx >> 6;
  ws[ET_OFF + idx] = expf(E[(size_t)s * NOBS + obs] - ws[LSE_OFF + s]);
}

// ---------------- forward recursion: 1 batch = 1 block = 1 wave ----------------
// Per step: 15 DPP rotations of alpha; 32 v_pk_fma (rows paired (g0,g1)/(g2,g3),
// rotated alpha lo-broadcast via op_sel) -> bitwise-identical chains to R7;
// permlane butterfly combine; select; emission mul. Rescale (exact pow-2) every
// 2 steps. Emissions staged to LDS per 64-step chunk (global_load_lds, double
// buffer, one vmcnt(0)/chunk) and consumed via exact-count lgkm ds_reads.

#define PINP(P) asm volatile("" : "+v"((P).x), "+v"((P).y))
#define PIN_ALL() do {                                                         \
    _Pragma("unroll")                                                          \
    for (int q_ = 0; q_ < 16; ++q_) { PINP(a01[q_]); PINP(a23[q_]); }          \
  } while (0)

// stage 64 emission rows of a chunk (x values in XS) into half HALF of ebuf
#define STAGE_CHUNK(XS, HALF) do {                                             \
    _Pragma("unroll")                                                          \
    for (int k_ = 0; k_ < 64; ++k_) {                                          \
      const int xt_ = __builtin_amdgcn_readlane((XS), k_);                     \
      const float* gp_ = ET + ((size_t)(unsigned)xt_ << 6) + lane;             \
      __builtin_amdgcn_global_load_lds(gp_, &ebuf[(((HALF) << 6) + k_) << 6],  \
                                       4, 0, 0);                               \
    } } while (0)

#define EREAD(DST, ADDR, IMM)                                                  \
  asm volatile("ds_read_b32 %0, %1 offset:" #IMM : "=v"(DST) : "v"(ADDR))

#define STEP(u, EC) do {                                                       \
    const int t_ = t0 + (u);                                                   \
    const float e_ = EC[(u)];                                                  \
    float es_;                                                                 \
    if (((u) & 1) != 0) { /* exact pow-2 rescale every 2 steps */              \
      const unsigned srf_ = __builtin_amdgcn_readfirstlane(__float_as_uint(s));\
      const int se_ = (int)((srf_ >> 23) & 0xFFu) - 127;                       \
      const float sc_ = __uint_as_float((unsigned)(127 - se_) << 23);          \
      es_ = e_ * sc_;                                                          \
      E2 += se_;                                                               \
    } else {                                                                   \
      es_ = e_;                                                                \
    }                                                                          \
    rot2[0].x = s;                                                             \
    rot2[1].x = DPPROR(s, 1);   rot2[2].x = DPPROR(s, 2);                      \
    rot2[3].x = DPPROR(s, 3);   rot2[4].x = DPPROR(s, 4);                      \
    rot2[5].x = DPPROR(s, 5);   rot2[6].x = DPPROR(s, 6);                      \
    rot2[7].x = DPPROR(s, 7);   rot2[8].x = DPPROR(s, 8);                      \
    rot2[9].x = DPPROR(s, 9);   rot2[10].x = DPPROR(s, 10);                    \
    rot2[11].x = DPPROR(s, 11); rot2[12].x = DPPROR(s, 12);                    \
    rot2[13].x = DPPROR(s, 13); rot2[14].x = DPPROR(s, 14);                    \
    rot2[15].x = DPPROR(s, 15);                                                \
    float2 ac01a, ac01b, ac23a, ac23b;                                         \
    PKMUL(ac01a, a01[0], rot2[0]);                                             \
    PKMUL(ac23a, a23[0], rot2[0]);                                             \
    PKMUL(ac01b, a01[8], rot2[8]);                                             \
    PKMUL(ac23b, a23[8], rot2[8]);                                             \
    _Pragma("unroll")                                                          \
    for (int j_ = 1; j_ < 8; ++j_) {                                           \
      PKFMA(ac01a, a01[j_],     rot2[j_]);                                     \
      PKFMA(ac23a, a23[j_],     rot2[j_]);                                     \
      PKFMA(ac01b, a01[8 + j_], rot2[8 + j_]);                                 \
      PKFMA(ac23b, a23[8 + j_], rot2[8 + j_]);                                 \
    }                                                                          \
    float2 s01_, s23_;                                                         \
    PKADD(s01_, ac01a, ac01b);                                                 \
    PKADD(s23_, ac23a, ac23b);                                                 \
    const float tot0_ = COMB(s01_.x);                                          \
    const float tot1_ = COMB(s01_.y);                                          \
    const float tot2_ = COMB(s23_.x);                                          \
    const float tot3_ = COMB(s23_.y);                                          \
    const float ta_ = (cgrp & 1) ? tot1_ : tot0_;                              \
    const float tb_ = (cgrp & 1) ? tot3_ : tot2_;                              \
    const float sel_ = (cgrp & 2) ? tb_ : ta_;                                 \
    const float w_ = es_ * ((t_ == 0) ? pip : sel_);                           \
    if (t_ == Tn - 1) { vs = w_; e2s = E2; }                                   \
    s = w_;                                                                    \
  } while (0)

// one 4-step group: issue next group's 4 e-reads, exact-wait current's, run 4
#define GROUP(T0, ECUR, ENXT) do {                                             \
    const int t0 = (T0);                                                       \
    { const unsigned ea_ =                                                     \
          ebase + ((unsigned)(((t0 + 4) & 127)) << 8) + ((unsigned)lane << 2); \
      EREAD(ENXT[0], ea_, 0);   EREAD(ENXT[1], ea_, 256);                      \
      EREAD(ENXT[2], ea_, 512); EREAD(ENXT[3], ea_, 768); }                    \
    asm volatile("s_waitcnt lgkmcnt(4)");                                      \
    __builtin_amdgcn_sched_barrier(0);                                         \
    STEP(0, ECUR); STEP(1, ECUR); STEP(2, ECUR); STEP(3, ECUR);                \
  } while (0)

__global__ void __attribute__((amdgpu_flat_work_group_size(64, 64)))
__attribute__((amdgpu_waves_per_eu(1, 1)))
hmm_fwd(const int* __restrict__ x, const int* __restrict__ T,
        const float* __restrict__ ws, float* __restrict__ out) {
  const int lane = threadIdx.x;
  const int b = blockIdx.x;
  const int cgrp = lane >> 4;
  const float* __restrict__ ET = ws + ET_OFF;
  const int* __restrict__ xb = x + (size_t)b * TMAX;
  const int Tn = T[b];

  __shared__ __align__(16) float ebuf[128 * 64];  // 32 KB, 2 chunk halves
  const unsigned ebase = (unsigned)(size_t)ebuf;  // flat->LDS trunc (aligned aperture)

  // pk-paired swizzled A tile for this lane, pinned resident in VGPR pairs
  float2 a01[16], a23[16];
  {
    const float4* ar = (const float4*)(ws + ASW_OFF + lane * NS);
#pragma unroll
    for (int q = 0; q < 8; ++q) {
      float4 f = ar[q];
      a01[2 * q]     = make_float2(f.x, f.y);
      a01[2 * q + 1] = make_float2(f.z, f.w);
    }
#pragma unroll
    for (int q = 0; q < 8; ++q) {
      float4 f = ar[8 + q];
      a23[2 * q]     = make_float2(f.x, f.y);
      a23[2 * q + 1] = make_float2(f.z, f.w);
    }
  }
  PIN_ALL();

  const float pip = ws[PIP_OFF + lane];

  // rot pairs: lo = rotated alpha (rewritten per step), hi = never read by HW
  // (op_sel broadcasts lo) but initialized once so the asm input is defined.
  float2 rot2[16];
#pragma unroll
  for (int j = 0; j < 16; ++j) rot2[j].y = 0.0f;

  // stage chunk 0, drain, prime group-0 e-reads
  int xcur = xb[lane];
  STAGE_CHUNK(xcur, 0);
  int xnext = xb[64 + lane];
  asm volatile("s_waitcnt vmcnt(0)" ::: "memory");

  float eA[4], eB[4];
  {
    const unsigned ea_ = ebase + ((unsigned)lane << 2);
    EREAD(eA[0], ea_, 0);   EREAD(eA[1], ea_, 256);
    EREAD(eA[2], ea_, 512); EREAD(eA[3], ea_, 768);
  }

  float s = 1.0f;   // exponent 0 -> se=0 at t=0
  float vs = 0.f;
  int E2 = 0, e2s = 0;

  const int nch = (Tn + 63) >> 6;
  for (int c = 0; c < nch; ++c) {
    const int tb = c << 6;
    if (c + 1 < TMAX / 64) STAGE_CHUNK(xnext, (c + 1) & 1);
    xnext = ((c + 2) < TMAX / 64) ? xb[((c + 2) << 6) + lane] : 0;
#pragma unroll 1
    for (int gp = 0; gp < 7; ++gp) {    // groups 0..13
      GROUP(tb + (gp << 3), eA, eB);
      GROUP(tb + (gp << 3) + 4, eB, eA);
    }
    GROUP(tb + 56, eA, eB);             // group 14
    // drain staging of chunk c+1 before group 15 issues next-chunk reads
    asm volatile("s_waitcnt vmcnt(0)" ::: "memory");
    GROUP(tb + 60, eB, eA);             // group 15 (loads eA for next chunk)
  }

  const float sf = wsum64(vs);
  if (lane == 0) {
    const double lp = (double)logf(sf) + (double)e2s * 0.6931471805599453;
    out[b] = (float)lp;
  }
}

extern "C" void kernel_launch(void* const* d_in, const int* in_sizes, int n_in,
                              void* d_out, int out_size, void* d_ws, size_t ws_size,
                              hipStream_t stream) {
  const int*   x  = (const int*)d_in[0];
  const int*   T  = (const int*)d_in[1];
  const float* pi = (const float*)d_in[2];
  const float* A  = (const float*)d_in[3];
  const float* E  = (const float*)d_in[4];
  float* out = (float*)d_out;
  float* ws  = (float*)d_ws;

  prep_small<<<1, 64, 0, stream>>>(pi, A, ws);
  emis_lse<<<NS, 256, 0, stream>>>(E, ws);
  emis_fill<<<(NS * NOBS + 255) / 256, 256, 0, stream>>>(E, ws);
  hmm_fwd<<<NB, 64, 0, stream>>>(x, T, ws, out);
}